// Round 18
// baseline (24.265 us; speedup 1.0000x reference)
//
#include <hip/hip_runtime.h>

#define HOP      256
#define SAMPLES  262144
#define NBINS    513
#define NFRAMES  1024
#define FPB      16   // frames per block, one wave per frame

typedef float v2f __attribute__((ext_vector_type(2)));

// -i * a  = (a.y, -a.x)
__device__ __forceinline__ v2f nI(v2f a) { v2f r = a.yx; r.y = -r.y; return r; }

// complex multiply
__device__ __forceinline__ v2f cmul2(v2f a, v2f b) {
  v2f bs = b.yx; bs.x = -bs.x;          // (-b.y, b.x)
  return a.xx * b + a.yy * bs;
}

__device__ __forceinline__ v2f lds_ld(const v2f* p, int bo) {
  return *(const v2f*)((const char*)p + bo);
}
__device__ __forceinline__ void lds_st(v2f* p, int bo, v2f v) {
  *(v2f*)((char*)p + bo) = v;
}
// swizzle: c = (H<<6)|(M<<3)|L -> (H<<6)|((M^(H&1))<<3)|(L^M)
__device__ __forceinline__ int swz(int c) {
  int H = c >> 6, M = (c >> 3) & 7, L = c & 7;
  return (H << 6) | ((M ^ (H & 1)) << 3) | (L ^ M);
}

// 8-point DFT, natural-order in/out, packed-f32 complex ops
__device__ __forceinline__ void fft8(v2f v[8]) {
  const float R = 0.70710678118654752440f;
  v2f s0 = v[0] + v[4], d0 = v[0] - v[4];
  v2f s1 = v[1] + v[5], d1 = v[1] - v[5];
  v2f s2 = v[2] + v[6], d2 = v[2] - v[6];
  v2f s3 = v[3] + v[7], d3 = v[3] - v[7];
  v2f e1 = R * (d1 + nI(d1));           // W8^1 * d1
  v2f e2 = nI(d2);                      // W8^2 * d2
  v2f e3 = R * (nI(d3) - d3);           // W8^3 * d3
  v2f p0 = s0 + s2, q0 = s0 - s2;
  v2f p1 = s1 + s3, q1 = s1 - s3;
  v2f q1t = nI(q1);
  v2f p2 = d0 + e2, q2 = d0 - e2;
  v2f p3 = e1 + e3, q3 = e1 - e3;
  v2f q3t = nI(q3);
  v[0] = p0 + p1;  v[4] = p0 - p1;
  v[2] = q0 + q1t; v[6] = q0 - q1t;
  v[1] = p2 + p3;  v[5] = p2 - p3;
  v[3] = q2 + q3t; v[7] = q2 - q3t;
}

// unpack one (frame, bin); Z pre-halved. X1 = Xe + tw*Xo; D = Xe - tw*Xo
#define UNPK(ZP, KEY, SK, SM, TW, X1, D) {                           \
    v2f Zk = lds_ld(ZP, ((SK) ^ (KEY)) << 3);                        \
    v2f Zm = lds_ld(ZP, ((SM) ^ (KEY)) << 3);                        \
    v2f mc = Zm; mc.y = -mc.y;                                       \
    v2f xe = Zk + mc;                                                \
    v2f xo = nI(Zk) + Zm.yx;                                         \
    v2f u  = cmul2(TW, xo);                                          \
    X1 = xe + u; D = xe - u; }

__global__ __launch_bounds__(1024, 8)   // VGPR<=64
void stft_kernel(const float* __restrict__ x, const float* __restrict__ win,
                 float* __restrict__ out) {
  __shared__ v2f z[FPB * 512];      // 64 KiB
  __shared__ v2f T1[7][64];         // stage-1 twiddles W512^{u*k}
  __shared__ v2f T2[7][8];          // stage-2 twiddles W64^{m*j}
  __shared__ v2f TU[256];           // unpack twiddles W1024^k, k<256
  __shared__ float WH[1024];        // 0.5 * window

  const int t  = threadIdx.x;
  const int b  = blockIdx.x >> 6;
  const int f0 = (blockIdx.x & 63) * FPB;
  const int w  = t >> 6;    // wave = frame-in-tile
  const int u  = t & 63;    // lane
  const int g  = u >> 3, m2l = u & 7;

  // ---- issue raw x loads first (HBM latency hides under table fill) ----
  const float* xb = x + (size_t)b * SAMPLES;
  const int base = (f0 + w) * HOP - 384;   // pad_left = 384
  v2f r[8];
  if (f0 != 0 && f0 != (NFRAMES - FPB)) {
    const v2f* xc = (const v2f*)(xb + base);
#pragma unroll
    for (int n1 = 0; n1 < 8; ++n1) r[n1] = xc[(n1 << 6) + u];
  } else {
#pragma unroll
    for (int n1 = 0; n1 < 8; ++n1) {
      int idx = base + (n1 << 7) + 2 * u;
      r[n1] = (v2f){0.f, 0.f};
      if (idx >= 0 && idx < SAMPLES) r[n1] = *(const v2f*)(xb + idx);
    }
  }

  // ---- cooperative table fill ----
  {
    WH[t] = 0.5f * win[t];
    float sn, cs;
    if (t < 448) {
      int k = t >> 6, uu = t & 63;
      __sincosf((float)(uu * (k + 1)) * (-6.28318530717958647693f / 512.f),
                &sn, &cs);
      T1[k][uu] = (v2f){cs, sn};
    } else if (t < 504) {
      int i = t - 448, k = i >> 3, m = i & 7;
      __sincosf((float)(m * (k + 1)) * (-6.28318530717958647693f / 64.f),
                &sn, &cs);
      T2[k][m] = (v2f){cs, sn};
    } else if (t >= 512 && t < 768) {
      int kk = t - 512;
      __sincosf((float)kk * (-6.28318530717958647693f / 1024.f), &sn, &cs);
      TU[kk] = (v2f){cs, sn};
    }
  }
  __syncthreads();

  // wave-burst decorrelation probe: stagger the 16 waves by ~64 cycles each
  // (s_sleep arg must be a constant -> constant-arg sleep in a runtime-count
  // loop). Max ramp 15*64 cyc ~= 0.4 us.
  #pragma nounroll
  for (int i = 0; i < w; ++i) __builtin_amdgcn_s_sleep(1);

  // ---------------- FFT phase: one wave per frame, all LDS intra-wave ------
  {
    v2f* zf = z + (w << 9);
    // closed-form swizzled addresses (bytes), derived from swz():
    const int A0    = (g << 3) | (m2l ^ g);
    const int B1w_e = (A0 ^ w) << 3;
    const int B1w_o = B1w_e ^ 64;
    const int C1    = (g << 6) | ((g & 1) << 3) | m2l;
    const int B1r   = (C1 ^ w) << 3;   // ex1 read / ex2 write: ^ (72*m1)
    const int D0    = (g << 6) | ((m2l ^ (g & 1)) << 3) | m2l;
    const int B2r   = (D0 ^ w) << 3;   // ex2 read: ^ (m<<3)
    const int F0    = (m2l << 3) | (g ^ m2l);
    const int B3_e  = (F0 ^ w) << 3;
    const int B3_o  = B3_e ^ 64;

    // window (pre-halved) from LDS — packed mul
    const v2f* wh2 = (const v2f*)WH;
#pragma unroll
    for (int n1 = 0; n1 < 8; ++n1) r[n1] = r[n1] * wh2[(n1 << 6) + u];

    // ---- stage 1: radix-8, twiddles from T1 ----
    fft8(r);
#pragma unroll
    for (int k = 1; k < 8; ++k) r[k] = cmul2(r[k], T1[k - 1][u]);
    lds_st(zf, B1w_e,        r[0]);
    lds_st(zf, B1w_o +  512, r[1]);
    lds_st(zf, B1w_e + 1024, r[2]);
    lds_st(zf, B1w_o + 1536, r[3]);
    lds_st(zf, B1w_e + 2048, r[4]);
    lds_st(zf, B1w_o + 2560, r[5]);
    lds_st(zf, B1w_e + 3072, r[6]);
    lds_st(zf, B1w_o + 3584, r[7]);

    // ex1 read: addr = B1r ^ 72*m1
    v2f y[8];
#pragma unroll
    for (int m1 = 0; m1 < 8; ++m1) y[m1] = lds_ld(zf, B1r ^ (72 * m1));

    // ---- stage 2: radix-8, twiddles from T2 ----
    fft8(y);
#pragma unroll
    for (int k = 1; k < 8; ++k) y[k] = cmul2(y[k], T2[k - 1][m2l]);
#pragma unroll
    for (int j1 = 0; j1 < 8; ++j1) lds_st(zf, B1r ^ (72 * j1), y[j1]);

    // ex2 read: addr = B2r ^ (m<<3)
    v2f h[8];
#pragma unroll
    for (int m = 0; m < 8; ++m) h[m] = lds_ld(zf, B2r ^ (m << 3));

    // ---- stage 3 + natural-order store ----
    fft8(h);
    lds_st(zf, B3_e,        h[0]);
    lds_st(zf, B3_o +  512, h[1]);
    lds_st(zf, B3_e + 1024, h[2]);
    lds_st(zf, B3_o + 1536, h[3]);
    lds_st(zf, B3_e + 2048, h[4]);
    lds_st(zf, B3_o + 2560, h[5]);
    lds_st(zf, B3_e + 3072, h[6]);
    lds_st(zf, B3_o + 3584, h[7]);
  }
  __syncthreads();

  // -------- unpack: frame-pair per thread, float2 stores, 2 bin-steps ------
  {
    const int f2i = t & 7;        // frame-pair index: 8 lanes span 16 frames
    const int q   = t >> 3;       // bin 0..127
    const int f   = f2i << 1;
    const int fr  = f0 + f;
    const v2f* zp0 = z + (f << 9);
    const v2f* zp1 = z + ((f + 1) << 9);

    const int sk0 = swz(q);
    const int sm0 = swz((512 - q) & 511);
    const int sk1 = sk0 + 128;                   // swz(q+128) = swz(q)+128
    const int sm1 = (q == 0) ? 384 : (sm0 - 128);// swz(384-q); q=0 -> swz(384)

    const v2f tw0 = TU[q];
    const v2f tw1 = TU[q + 128];
    float* out_r = out;
    float* out_i = out + (size_t)16 * NBINS * NFRAMES;
    const size_t o1 = ((size_t)b * NBINS + q) * NFRAMES + fr;
    const size_t o2 = ((size_t)b * NBINS + (512 - q)) * NFRAMES + fr;
    const size_t STP = (size_t)128 * NFRAMES;

    // ---- k = q ----
    {
      v2f X1a, Da, X1b, Db;
      UNPK(zp0, f,     sk0, sm0, tw0, X1a, Da)
      UNPK(zp1, f + 1, sk0, sm0, tw0, X1b, Db)
      *(v2f*)(out_r + o1) = (v2f){X1a.x, X1b.x};
      *(v2f*)(out_i + o1) = (v2f){X1a.y, X1b.y};
      *(v2f*)(out_r + o2) = (v2f){Da.x, Db.x};
      *(v2f*)(out_i + o2) = (v2f){-Da.y, -Db.y};
    }
    // ---- k = q + 128 ----
    {
      v2f X1a, Da, X1b, Db;
      UNPK(zp0, f,     sk1, sm1, tw1, X1a, Da)
      UNPK(zp1, f + 1, sk1, sm1, tw1, X1b, Db)
      *(v2f*)(out_r + o1 + STP) = (v2f){X1a.x, X1b.x};
      *(v2f*)(out_i + o1 + STP) = (v2f){X1a.y, X1b.y};
      *(v2f*)(out_r + o2 - STP) = (v2f){Da.x, Db.x};
      *(v2f*)(out_i + o2 - STP) = (v2f){-Da.y, -Db.y};
    }
    // ---- edge bin 256: X[256] = conj(Z[256]) = conj(2*Z') ----
    if (q == 0) {
      v2f Za = lds_ld(zp0, (256 ^ f) << 3);
      v2f Zb = lds_ld(zp1, (256 ^ (f + 1)) << 3);
      const size_t o6 = ((size_t)b * NBINS + 256) * NFRAMES + fr;
      *(v2f*)(out_r + o6) = (v2f){Za.x + Za.x, Zb.x + Zb.x};
      *(v2f*)(out_i + o6) = (v2f){-(Za.y + Za.y), -(Zb.y + Zb.y)};
    }
  }
}

extern "C" void kernel_launch(void* const* d_in, const int* in_sizes, int n_in,
                              void* d_out, int out_size, void* d_ws, size_t ws_size,
                              hipStream_t stream) {
  const float* x = (const float*)d_in[0];
  const float* w = (const float*)d_in[1];
  float* out = (float*)d_out;
  (void)in_sizes; (void)n_in; (void)out_size; (void)d_ws; (void)ws_size;
  stft_kernel<<<dim3(1024), dim3(1024), 0, stream>>>(x, w, out);
}

// Round 20
// 22.810 us; speedup vs baseline: 1.0638x; 1.0638x over previous
//
#include <hip/hip_runtime.h>

#define HOP      256
#define SAMPLES  262144
#define NBINS    513
#define NFRAMES  1024
#define FPB      16   // frames per block; 8 waves x 2 frames each

typedef float  v2f __attribute__((ext_vector_type(2)));
typedef __fp16 h2  __attribute__((ext_vector_type(2)));

__device__ __forceinline__ v2f nI(v2f a) { v2f r = a.yx; r.y = -r.y; return r; }
__device__ __forceinline__ v2f cmul2(v2f a, v2f b) {
  v2f bs = b.yx; bs.x = -bs.x;
  return a.xx * b + a.yy * bs;
}

// fp16-packed LDS accessors (byte offsets; one h2 = one complex = 4B)
__device__ __forceinline__ void lds_st16(h2* p, int bo, v2f v) {
  *(h2*)((char*)p + bo) = __builtin_amdgcn_cvt_pkrtz(v.x, v.y);
}
__device__ __forceinline__ v2f lds_ld16(const h2* p, int bo) {
  h2 h = *(const h2*)((const char*)p + bo);
  return (v2f){(float)h.x, (float)h.y};
}
// swizzle: c = (H<<6)|(M<<3)|L -> (H<<6)|((M^(H&1))<<3)|(L^M)
__device__ __forceinline__ int swz(int c) {
  int H = c >> 6, M = (c >> 3) & 7, L = c & 7;
  return (H << 6) | ((M ^ (H & 1)) << 3) | (L ^ M);
}

// 8-point DFT, natural-order in/out, packed-f32 complex ops
__device__ __forceinline__ void fft8(v2f v[8]) {
  const float R = 0.70710678118654752440f;
  v2f s0 = v[0] + v[4], d0 = v[0] - v[4];
  v2f s1 = v[1] + v[5], d1 = v[1] - v[5];
  v2f s2 = v[2] + v[6], d2 = v[2] - v[6];
  v2f s3 = v[3] + v[7], d3 = v[3] - v[7];
  v2f e1 = R * (d1 + nI(d1));
  v2f e2 = nI(d2);
  v2f e3 = R * (nI(d3) - d3);
  v2f p0 = s0 + s2, q0 = s0 - s2;
  v2f p1 = s1 + s3, q1 = s1 - s3;
  v2f q1t = nI(q1);
  v2f p2 = d0 + e2, q2 = d0 - e2;
  v2f p3 = e1 + e3, q3 = e1 - e3;
  v2f q3t = nI(q3);
  v[0] = p0 + p1;  v[4] = p0 - p1;
  v[2] = q0 + q1t; v[6] = q0 - q1t;
  v[1] = p2 + p3;  v[5] = p2 - p3;
  v[3] = q2 + q3t; v[7] = q2 - q3t;
}

// stage 1: fft8 + T1 twiddles + ex1 write (E/O byte bases, 256B per k1)
#define FFT_S1(R, ZF, E1, O1) {                                          \
    fft8(R);                                                             \
    _Pragma("unroll")                                                    \
    for (int k = 1; k < 8; ++k) R[k] = cmul2(R[k], T1[k - 1][u]);        \
    lds_st16(ZF, (E1),        R[0]);                                     \
    lds_st16(ZF, (O1) +  256, R[1]);                                     \
    lds_st16(ZF, (E1) +  512, R[2]);                                     \
    lds_st16(ZF, (O1) +  768, R[3]);                                     \
    lds_st16(ZF, (E1) + 1024, R[4]);                                     \
    lds_st16(ZF, (O1) + 1280, R[5]);                                     \
    lds_st16(ZF, (E1) + 1536, R[6]);                                     \
    lds_st16(ZF, (O1) + 1792, R[7]);                                     \
  }

// stage 2: ex1 read + fft8 + T2 twiddles + ex2 write (in-place)
#define FFT_S2(Y, ZF, BR) {                                              \
    _Pragma("unroll")                                                    \
    for (int m1 = 0; m1 < 8; ++m1) Y[m1] = lds_ld16(ZF, (BR) ^ (36*m1)); \
    fft8(Y);                                                             \
    _Pragma("unroll")                                                    \
    for (int k = 1; k < 8; ++k) Y[k] = cmul2(Y[k], T2[k - 1][m2l]);      \
    _Pragma("unroll")                                                    \
    for (int j1 = 0; j1 < 8; ++j1) lds_st16(ZF, (BR) ^ (36*j1), Y[j1]);  \
  }

// stage 3: ex2 read + fft8 + natural-order store
#define FFT_S3(H, ZF, B2, E3, O3) {                                      \
    _Pragma("unroll")                                                    \
    for (int m = 0; m < 8; ++m) H[m] = lds_ld16(ZF, (B2) ^ (m << 2));    \
    fft8(H);                                                             \
    lds_st16(ZF, (E3),        H[0]);                                     \
    lds_st16(ZF, (O3) +  256, H[1]);                                     \
    lds_st16(ZF, (E3) +  512, H[2]);                                     \
    lds_st16(ZF, (O3) +  768, H[3]);                                     \
    lds_st16(ZF, (E3) + 1024, H[4]);                                     \
    lds_st16(ZF, (O3) + 1280, H[5]);                                     \
    lds_st16(ZF, (E3) + 1536, H[6]);                                     \
    lds_st16(ZF, (O3) + 1792, H[7]);                                     \
  }

// unpack one (frame, bin); z pre-halved. X1 = Xe + tw*Xo; D = Xe - tw*Xo
#define UNPK(ZP, KEY, SK, SM, TW, X1, D) {                           \
    v2f Zk = lds_ld16(ZP, ((SK) ^ (KEY)) << 2);                      \
    v2f Zm = lds_ld16(ZP, ((SM) ^ (KEY)) << 2);                      \
    v2f mc = Zm; mc.y = -mc.y;                                       \
    v2f xe = Zk + mc;                                                \
    v2f xo = nI(Zk) + Zm.yx;                                         \
    v2f uu = cmul2(TW, xo);                                          \
    X1 = xe + uu; D = xe - uu; }

__global__ __launch_bounds__(512, 8)   // VGPR<=64; target 4 blocks/CU (38KiB LDS)
void stft_kernel(const float* __restrict__ x, const float* __restrict__ win,
                 float* __restrict__ out) {
  __shared__ h2  z[FPB * 512];      // 32 KiB (fp16 complex)
  __shared__ v2f T1[7][64];         // stage-1 twiddles W512^{u*k} (f32)
  __shared__ v2f T2[7][8];          // stage-2 twiddles W64^{m*j}
  __shared__ v2f TU[256];           // unpack twiddles W1024^k

  const int t  = threadIdx.x;
  const int b  = blockIdx.x >> 6;
  const int f0 = (blockIdx.x & 63) * FPB;
  const int w2 = t >> 6;    // wave -> frames w2 and w2+8
  const int u  = t & 63;    // lane
  const int g  = u >> 3, m2l = u & 7;

  // ---- issue raw x loads for both frames first (latency under table fill) --
  const float* xb = x + (size_t)b * SAMPLES;
  const int baseA = (f0 + w2) * HOP - 384;   // pad_left = 384
  const int baseB = baseA + 8 * HOP;
  v2f ra[8], rb[8];
  if (f0 != 0) {
    const v2f* xc = (const v2f*)(xb + baseA);
#pragma unroll
    for (int n1 = 0; n1 < 8; ++n1) ra[n1] = xc[(n1 << 6) + u];
  } else {
#pragma unroll
    for (int n1 = 0; n1 < 8; ++n1) {
      int idx = baseA + (n1 << 7) + 2 * u;
      ra[n1] = (v2f){0.f, 0.f};
      if (idx >= 0) ra[n1] = *(const v2f*)(xb + idx);
    }
  }
  if (f0 != (NFRAMES - FPB)) {
    const v2f* xc = (const v2f*)(xb + baseB);
#pragma unroll
    for (int n1 = 0; n1 < 8; ++n1) rb[n1] = xc[(n1 << 6) + u];
  } else {
#pragma unroll
    for (int n1 = 0; n1 < 8; ++n1) {
      int idx = baseB + (n1 << 7) + 2 * u;
      rb[n1] = (v2f){0.f, 0.f};
      if (idx < SAMPLES) rb[n1] = *(const v2f*)(xb + idx);
    }
  }

  // ---- cooperative table fill (512 threads; low threads fill TU too) ----
  {
    float sn, cs;
    if (t < 448) {
      int k = t >> 6, uu2 = t & 63;
      __sincosf((float)(uu2 * (k + 1)) * (-6.28318530717958647693f / 512.f),
                &sn, &cs);
      T1[k][uu2] = (v2f){cs, sn};
    } else if (t < 504) {
      int i = t - 448, k = i >> 3, m = i & 7;
      __sincosf((float)(m * (k + 1)) * (-6.28318530717958647693f / 64.f),
                &sn, &cs);
      T2[k][m] = (v2f){cs, sn};
    }
    if (t < 256) {
      __sincosf((float)t * (-6.28318530717958647693f / 1024.f), &sn, &cs);
      TU[t] = (v2f){cs, sn};
    }
  }
  __syncthreads();

  // ---------------- FFT phase: each wave does frames w2 and w2+8 ----------
  {
    h2* zfA = z + (w2 << 9);
    h2* zfB = z + ((w2 + 8) << 9);
    // closed-form swizzled byte addresses (4B slots now: slot<<2)
    const int A0    = (g << 3) | (m2l ^ g);
    const int B1w_e = (A0 ^ w2) << 2;
    const int B1w_o = B1w_e ^ 32;
    const int C1    = (g << 6) | ((g & 1) << 3) | m2l;
    const int B1r   = (C1 ^ w2) << 2;   // ex1 read / ex2 write: ^ (36*m1)
    const int D0    = (g << 6) | ((m2l ^ (g & 1)) << 3) | m2l;
    const int B2r   = (D0 ^ w2) << 2;   // ex2 read: ^ (m<<2)
    const int F0    = (m2l << 3) | (g ^ m2l);
    const int B3_e  = (F0 ^ w2) << 2;
    const int B3_o  = B3_e ^ 32;

    // window both frames; fold the 0.5 rfft factor (shared loads)
    const v2f* wc = (const v2f*)win;
#pragma unroll
    for (int n1 = 0; n1 < 8; ++n1) {
      v2f wv = wc[(n1 << 6) + u] * 0.5f;
      ra[n1] = ra[n1] * wv;
      rb[n1] = rb[n1] * wv;
    }

    // frame B key = w2^8 -> all byte offsets ^32 (E/O swapped)
    FFT_S1(ra, zfA, B1w_e, B1w_o)
    FFT_S1(rb, zfB, B1w_o, B1w_e)
    {
      v2f y[8];
      FFT_S2(y, zfA, B1r)
      v2f y2[8];
      FFT_S2(y2, zfB, B1r ^ 32)
    }
    {
      v2f h_[8];
      FFT_S3(h_, zfA, B2r, B3_e, B3_o)
      v2f h2_[8];
      FFT_S3(h2_, zfB, B2r ^ 32, B3_o, B3_e)
    }
  }
  __syncthreads();

  // -------- unpack: frame-pair per thread, qq in {q, q+64} -----------------
  {
    const int f2i = t & 7;        // 8 frame-pairs span 16 frames
    const int q   = t >> 3;       // bin residue 0..63
    const int f   = f2i << 1;
    const int fr  = f0 + f;
    const h2* zp0 = z + (f << 9);
    const h2* zp1 = z + ((f + 1) << 9);
    float* out_r = out;
    float* out_i = out + (size_t)16 * NBINS * NFRAMES;
    const size_t STP = (size_t)128 * NFRAMES;

#pragma unroll
    for (int hh = 0; hh < 2; ++hh) {
      const int qq  = q + (hh << 6);
      const int sk0 = swz(qq);
      const int sm0 = swz((512 - qq) & 511);
      const int sk1 = sk0 + 128;                    // swz(qq+128)
      const int sm1 = (qq == 0) ? 384 : (sm0 - 128);// swz(384-qq)
      const v2f tw0 = TU[qq];
      const v2f tw1 = TU[qq + 128];
      const size_t o1 = ((size_t)b * NBINS + qq) * NFRAMES + fr;
      const size_t o2 = ((size_t)b * NBINS + (512 - qq)) * NFRAMES + fr;

      // ---- k = qq ----
      {
        v2f X1a, Da, X1b, Db;
        UNPK(zp0, f,     sk0, sm0, tw0, X1a, Da)
        UNPK(zp1, f + 1, sk0, sm0, tw0, X1b, Db)
        *(v2f*)(out_r + o1) = (v2f){X1a.x, X1b.x};
        *(v2f*)(out_i + o1) = (v2f){X1a.y, X1b.y};
        *(v2f*)(out_r + o2) = (v2f){Da.x, Db.x};
        *(v2f*)(out_i + o2) = (v2f){-Da.y, -Db.y};
      }
      // ---- k = qq + 128 ----
      {
        v2f X1a, Da, X1b, Db;
        UNPK(zp0, f,     sk1, sm1, tw1, X1a, Da)
        UNPK(zp1, f + 1, sk1, sm1, tw1, X1b, Db)
        *(v2f*)(out_r + o1 + STP) = (v2f){X1a.x, X1b.x};
        *(v2f*)(out_i + o1 + STP) = (v2f){X1a.y, X1b.y};
        *(v2f*)(out_r + o2 - STP) = (v2f){Da.x, Db.x};
        *(v2f*)(out_i + o2 - STP) = (v2f){-Da.y, -Db.y};
      }
    }
    // ---- edge bin 256: X[256] = conj(Z[256]) = conj(2*Z') ----
    if (q == 0) {
      v2f Za = lds_ld16(zp0, (256 ^ f) << 2);
      v2f Zb = lds_ld16(zp1, (256 ^ (f + 1)) << 2);
      const size_t o6 = ((size_t)b * NBINS + 256) * NFRAMES + fr;
      *(v2f*)(out_r + o6) = (v2f){Za.x + Za.x, Zb.x + Zb.x};
      *(v2f*)(out_i + o6) = (v2f){-(Za.y + Za.y), -(Zb.y + Zb.y)};
    }
  }
}

extern "C" void kernel_launch(void* const* d_in, const int* in_sizes, int n_in,
                              void* d_out, int out_size, void* d_ws, size_t ws_size,
                              hipStream_t stream) {
  const float* x = (const float*)d_in[0];
  const float* w = (const float*)d_in[1];
  float* out = (float*)d_out;
  (void)in_sizes; (void)n_in; (void)out_size; (void)d_ws; (void)ws_size;
  stft_kernel<<<dim3(1024), dim3(512), 0, stream>>>(x, w, out);
}